// Round 4
// baseline (278.251 us; speedup 1.0000x reference)
//
#include <hip/hip_runtime.h>

typedef _Float16 f16;
typedef f16 f16x2 __attribute__((ext_vector_type(2)));
typedef f16 f16x4 __attribute__((ext_vector_type(4)));
typedef f16 f16x8 __attribute__((ext_vector_type(8)));
typedef float f32x4 __attribute__((ext_vector_type(4)));

#define NB   2
#define LL   2048
#define LQ   2048         // q tokens per scrambled batch
#define LKV  512          // unique kv tokens per scrambled batch
#define DD   128
#define BM   128          // q tokens per block (4 waves x 32)
#define BN   64           // kv tokens per iteration
#define NKT  (LKV/BN)     // 8
#define PT_STR 68         // halves per Pt row (64+4)
// fallback-kernel params (first verified kernel)
#define KS_STR 132
#define VT_STR 68

// workspace layout (halves): K16[g 64][kv 512][d 128] then V16t[g 64][d 128][kv 512]
#define G_STRIDE 65536ull          // halves per g per tensor
#define WS_BYTES (2ull*64ull*G_STRIDE*2ull)   // 16,777,216 B

// ---------------------------------------------------------------------------
// Pre-pass: K -> f16 (plain [kv][d] layout), V -> f16 transposed ([d][kv 512]).
// Done ONCE so the 16 q-blocks per g don't re-convert; K/V (16 MB total) stay
// L2/L3-resident for the main kernel's direct register loads.
// ---------------------------------------------------------------------------
__global__ __launch_bounds__(256)
void prepack(const float* __restrict__ kg, const float* __restrict__ vg,
             f16* __restrict__ ws)
{
    __shared__ float vtile[64*132];            // f32 staging for V transpose
    const int tid = threadIdx.x;
    const int kt  = blockIdx.x;                // 0..7 (64-row kv tile)
    const int g   = blockIdx.y;                // 0..63 (slice offset = g*65536 floats)

    if (blockIdx.z == 0) {
        // K: straight convert-copy, fully coalesced
        const float* kb = kg + (size_t)g*65536 + (size_t)kt*8192;  // [64][128] tile
        f16* kout = ws + (size_t)g*G_STRIDE + (size_t)kt*8192;
#pragma unroll
        for (int i = 0; i < 8; ++i) {
            int f = tid + i*256;               // 0..2047, 4 floats each
            float4 x = *(const float4*)(kb + (size_t)f*4);
            f16x4 h = { (f16)x.x,(f16)x.y,(f16)x.z,(f16)x.w };
            *(f16x4*)(kout + (size_t)f*4) = h;
        }
    } else {
        // V: transpose tile via LDS -> Vt[g][d 128][kv 512] (row stride 512)
        const float* vb = vg + (size_t)g*65536 + (size_t)kt*8192;  // [64 kv][128 d]
        f16* vout = ws + 64ull*G_STRIDE + (size_t)g*G_STRIDE;
#pragma unroll
        for (int i = 0; i < 8; ++i) {
            int f = tid + i*256;
            int row = f >> 5, c4 = f & 31;
            float4 x = *(const float4*)(vb + (size_t)f*4);
            *(float4*)(vtile + row*132 + c4*4) = x;
        }
        __syncthreads();
#pragma unroll
        for (int i = 0; i < 4; ++i) {
            int q = i*256 + tid;               // 0..1023
            int r = q >> 3, c = q & 7;         // r = d row (0..127), c = kv chunk of 8
            f16x8 h;
#pragma unroll
            for (int j = 0; j < 8; ++j) h[j] = (f16)vtile[(c*8+j)*132 + r];
            *(f16x8*)(vout + (size_t)r*LKV + kt*64 + c*8) = h;
        }
    }
}

// ---------------------------------------------------------------------------
// Main flash-attention kernel — ZERO barriers, zero K/V staging.
// Each lane loads its MFMA fragments directly from the prepacked f16 workspace
// (contiguous aligned 16B per lane; a wave covers each 16KB tile exactly once;
// K/V are L2-resident). Pt (P round-trip for the PV B-operand) is the only LDS
// and is wave-private rows, so waves run as fully independent pipelines.
// ---------------------------------------------------------------------------
__global__ __launch_bounds__(256, 3)
void fa_fwd(const float* __restrict__ qg, const f16* __restrict__ ws,
            float* __restrict__ og)
{
    __shared__ __align__(16) f16 Pt[BM*PT_STR];   // [128][68], 17408 B (only LDS)

    const int tid  = threadIdx.x;
    const int wave = tid >> 6;
    const int lane = tid & 63;
    const int ln   = lane & 15;
    const int qd   = lane >> 4;

    // XCD-aware decode: all 16 q-blocks of a batch g share an XCD (bid%8 fixed).
    const int bid = blockIdx.x;                 // 0..1023
    const int qt  = (bid >> 3) & 15;
    const int g   = ((bid & 7) << 3) | (bid >> 7);
    const int bb  = g >> 5;
    const int lhi = g & 31;

    const float* qmat = qg + (size_t)(bb*LL + 64*lhi)*4096;  // [2048][128] f32
    const f16*   kw   = ws + (size_t)g*G_STRIDE;             // [512][128] f16
    const f16*   vw   = ws + (64ull + (size_t)g)*G_STRIDE;   // [128][512] f16 (V^T)

    const int qbase = qt*BM + wave*32;

    // Q fragments: B-operand of S^T=K*Q^T. frag(nt,kc) slot j = Q''[qbase+16nt+ln][32kc+8qd+j]
    f16x8 qf[2][4];
#pragma unroll
    for (int nt = 0; nt < 2; ++nt) {
        const float* qrow = qmat + (size_t)(qbase + 16*nt + ln)*DD;
#pragma unroll
        for (int kc = 0; kc < 4; ++kc) {
            const float4* qp = (const float4*)(qrow + kc*32 + 8*qd);
            float4 f0 = qp[0], f1 = qp[1];
            f16x8 t = { (f16)f0.x,(f16)f0.y,(f16)f0.z,(f16)f0.w,
                        (f16)f1.x,(f16)f1.y,(f16)f1.z,(f16)f1.w };
            qf[nt][kc] = t;
        }
    }

    f32x4 o[2][8];   // o[nt][dmt][r] = O^T[16*dmt+4*qd+r][q(nt)]
#pragma unroll
    for (int nt = 0; nt < 2; ++nt)
#pragma unroll
        for (int dmt = 0; dmt < 8; ++dmt)
#pragma unroll
            for (int r = 0; r < 4; ++r) o[nt][dmt][r] = 0.0f;

    float mrun[2] = {-1e30f, -1e30f}, lrun[2] = {0.0f, 0.0f};
    const float SC2 = 0.08837890625f * 1.44269504088896340f;  // fp16-rounded scale * log2(e)

#pragma unroll 1
    for (int t = 0; t < NKT; ++t) {
        // ---- S^T = K*Q^T : K fragments straight from L2 (16B/lane, tile covered 1x) ----
        f32x4 st[2][4];  // st[nt][mt][r] = S^T[16*mt+4*qd+r][q(nt)]
#pragma unroll
        for (int nt = 0; nt < 2; ++nt)
#pragma unroll
            for (int mt = 0; mt < 4; ++mt)
#pragma unroll
                for (int r = 0; r < 4; ++r) st[nt][mt][r] = 0.0f;
        __builtin_amdgcn_s_setprio(1);
#pragma unroll
        for (int mt = 0; mt < 4; ++mt) {
            const f16* kr = kw + (size_t)(t*BN + 16*mt + ln)*DD + 8*qd;
#pragma unroll
            for (int kc = 0; kc < 4; ++kc) {
                f16x8 af = *(const f16x8*)(kr + kc*32);
#pragma unroll
                for (int nt = 0; nt < 2; ++nt)
                    st[nt][mt] = __builtin_amdgcn_mfma_f32_16x16x32_f16(af, qf[nt][kc], st[nt][mt], 0,0,0);
            }
        }
        __builtin_amdgcn_s_setprio(0);

        // ---- online softmax (registers only) ----
        float alph[2];
#pragma unroll
        for (int nt = 0; nt < 2; ++nt) {
            float mx = -1e30f;
#pragma unroll
            for (int mt = 0; mt < 4; ++mt)
#pragma unroll
                for (int r = 0; r < 4; ++r) {
                    float v = st[nt][mt][r]*SC2; st[nt][mt][r] = v; mx = fmaxf(mx, v);
                }
            mx = fmaxf(mx, __shfl_xor(mx, 16, 64));
            mx = fmaxf(mx, __shfl_xor(mx, 32, 64));
            float mnew = fmaxf(mrun[nt], mx);
            alph[nt] = exp2f(mrun[nt] - mnew);
            float rs = 0.0f;
#pragma unroll
            for (int mt = 0; mt < 4; ++mt)
#pragma unroll
                for (int r = 0; r < 4; ++r) {
                    float p = exp2f(st[nt][mt][r] - mnew);
                    st[nt][mt][r] = p; rs += p;
                }
            rs += __shfl_xor(rs, 16, 64);
            rs += __shfl_xor(rs, 32, 64);
            lrun[nt] = lrun[nt]*alph[nt] + rs;
            mrun[nt] = mnew;
        }

        // ---- P -> LDS (wave-private rows; same-wave write->read, no barrier) ----
#pragma unroll
        for (int nt = 0; nt < 2; ++nt) {
            f16* prow = Pt + (wave*32 + 16*nt + ln)*PT_STR + 4*qd;
#pragma unroll
            for (int mt = 0; mt < 4; ++mt)
#pragma unroll
                for (int p2 = 0; p2 < 2; ++p2) {
                    f16x2 pp = { (f16)st[nt][mt][2*p2], (f16)st[nt][mt][2*p2+1] };
                    *(f16x2*)(prow + 16*mt + 2*p2) = pp;
                }
        }

        // ---- rescale O^T ----
#pragma unroll
        for (int nt = 0; nt < 2; ++nt)
#pragma unroll
            for (int dmt = 0; dmt < 8; ++dmt)
#pragma unroll
                for (int r = 0; r < 4; ++r) o[nt][dmt][r] *= alph[nt];

        // ---- O^T += V^T * P^T : V^T fragments straight from L2, P from Pt ----
#pragma unroll
        for (int kc2 = 0; kc2 < 2; ++kc2) {
            f16x8 pf[2];
#pragma unroll
            for (int nt = 0; nt < 2; ++nt) {
                const f16* pr = Pt + (wave*32 + 16*nt + ln)*PT_STR + kc2*32 + 8*qd;
                f16x4 b0 = *(const f16x4*)(pr);
                f16x4 b1 = *(const f16x4*)(pr + 4);
                pf[nt] = __builtin_shufflevector(b0, b1, 0,1,2,3,4,5,6,7);
            }
            __builtin_amdgcn_s_setprio(1);
#pragma unroll
            for (int dmt = 0; dmt < 8; ++dmt) {
                f16x8 vf = *(const f16x8*)(vw + (size_t)(16*dmt + ln)*LKV
                                              + t*BN + kc2*32 + 8*qd);
#pragma unroll
                for (int nt = 0; nt < 2; ++nt)
                    o[nt][dmt] = __builtin_amdgcn_mfma_f32_16x16x32_f16(vf, pf[nt], o[nt][dmt], 0,0,0);
            }
            __builtin_amdgcn_s_setprio(0);
        }
    }

    // ---- epilogue: O^T/l -> og[(bb*2048+t)*4096 + lhi*128 + d] ----
#pragma unroll
    for (int nt = 0; nt < 2; ++nt) {
        float inv = 1.0f / lrun[nt];
        int qtok = qbase + 16*nt + ln;
        float* orow = og + (size_t)(bb*LL + qtok)*4096 + lhi*DD + 4*qd;
#pragma unroll
        for (int dmt = 0; dmt < 8; ++dmt) {
            float4 x = { o[nt][dmt][0]*inv, o[nt][dmt][1]*inv,
                         o[nt][dmt][2]*inv, o[nt][dmt][3]*inv };
            *(float4*)(orow + 16*dmt) = x;
        }
    }
}

// ---------------------------------------------------------------------------
// Fallback (first verified kernel) for the case ws_size < WS_BYTES.
// ---------------------------------------------------------------------------
__global__ __launch_bounds__(256, 2)
void fa_fwd_fb(const float* __restrict__ qg,
               const float* __restrict__ kg,
               const float* __restrict__ vg,
               float* __restrict__ og)
{
    __shared__ __align__(16) f16 smem[BN*KS_STR + DD*VT_STR + BM*PT_STR];
    f16* Ks = smem;
    f16* Vt = smem + BN*KS_STR;
    f16* Pt = smem + BN*KS_STR + DD*VT_STR;

    const int tid  = threadIdx.x;
    const int wave = tid >> 6;
    const int lane = tid & 63;
    const int ln   = lane & 15;
    const int qd   = lane >> 4;

    const int qt   = blockIdx.x;
    const int g    = blockIdx.y;
    const int bb   = g >> 5;
    const int lhi  = g & 31;

    const float* qmat = qg + (size_t)(bb*LL + 64*lhi)*4096;
    const float* kmat = kg + (size_t)(bb*LL + 64*lhi)*1024;
    const float* vmat = vg + (size_t)(bb*LL + 64*lhi)*1024;

    const int qbase = qt*BM + wave*32;

    f16x8 qf[2][4];
#pragma unroll
    for (int nt = 0; nt < 2; ++nt) {
        const float* qrow = qmat + (size_t)(qbase + 16*nt + ln)*DD;
#pragma unroll
        for (int kc = 0; kc < 4; ++kc) {
            const float4* qp = (const float4*)(qrow + kc*32 + 8*qd);
            float4 f0 = qp[0], f1 = qp[1];
            f16x8 t = { (f16)f0.x,(f16)f0.y,(f16)f0.z,(f16)f0.w,
                        (f16)f1.x,(f16)f1.y,(f16)f1.z,(f16)f1.w };
            qf[nt][kc] = t;
        }
    }

    f32x4 o[2][8];
#pragma unroll
    for (int nt = 0; nt < 2; ++nt)
#pragma unroll
        for (int dmt = 0; dmt < 8; ++dmt)
#pragma unroll
            for (int r = 0; r < 4; ++r) o[nt][dmt][r] = 0.0f;

    float mrun[2] = {-1e30f, -1e30f}, lrun[2] = {0.0f, 0.0f};
    const float SC2 = 0.08837890625f * 1.44269504088896340f;

    for (int kt = 0; kt < LKV/BN; ++kt) {
        const float* kb = kmat + kt*BN*DD;
        const float* vb = vmat + kt*BN*DD;

#pragma unroll
        for (int i = 0; i < 8; ++i) {
            int f = tid + i*256;
            int row = f >> 5, c4 = f & 31;
            float4 x = *(const float4*)(kb + f*4);
            f16x4 h4 = { (f16)x.x,(f16)x.y,(f16)x.z,(f16)x.w };
            *(f16x4*)(Ks + row*KS_STR + c4*4) = h4;
        }
#pragma unroll
        for (int i = 0; i < 8; ++i) {
            int f = tid + i*256;
            int kvr = f & 63, c4 = f >> 6;
            float4 x = *(const float4*)(vb + (size_t)kvr*DD + c4*4);
            Vt[(c4*4+0)*VT_STR + kvr] = (f16)x.x;
            Vt[(c4*4+1)*VT_STR + kvr] = (f16)x.y;
            Vt[(c4*4+2)*VT_STR + kvr] = (f16)x.z;
            Vt[(c4*4+3)*VT_STR + kvr] = (f16)x.w;
        }
        __syncthreads();

        f32x4 st[2][4];
#pragma unroll
        for (int nt = 0; nt < 2; ++nt)
#pragma unroll
            for (int mt = 0; mt < 4; ++mt)
#pragma unroll
                for (int r = 0; r < 4; ++r) st[nt][mt][r] = 0.0f;
#pragma unroll
        for (int mt = 0; mt < 4; ++mt) {
            const f16* kr = Ks + (16*mt + ln)*KS_STR + 8*qd;
#pragma unroll
            for (int kc = 0; kc < 4; ++kc) {
                f16x4 a0 = *(const f16x4*)(kr + kc*32);
                f16x4 a1 = *(const f16x4*)(kr + kc*32 + 4);
                f16x8 af = __builtin_shufflevector(a0, a1, 0,1,2,3,4,5,6,7);
#pragma unroll
                for (int nt = 0; nt < 2; ++nt)
                    st[nt][mt] = __builtin_amdgcn_mfma_f32_16x16x32_f16(af, qf[nt][kc], st[nt][mt], 0,0,0);
            }
        }

        float alph[2];
#pragma unroll
        for (int nt = 0; nt < 2; ++nt) {
            float mx = -1e30f;
#pragma unroll
            for (int mt = 0; mt < 4; ++mt)
#pragma unroll
                for (int r = 0; r < 4; ++r) {
                    float v = st[nt][mt][r]*SC2; st[nt][mt][r] = v; mx = fmaxf(mx, v);
                }
            mx = fmaxf(mx, __shfl_xor(mx, 16, 64));
            mx = fmaxf(mx, __shfl_xor(mx, 32, 64));
            float mnew = fmaxf(mrun[nt], mx);
            alph[nt] = exp2f(mrun[nt] - mnew);
            float rs = 0.0f;
#pragma unroll
            for (int mt = 0; mt < 4; ++mt)
#pragma unroll
                for (int r = 0; r < 4; ++r) {
                    float p = exp2f(st[nt][mt][r] - mnew);
                    st[nt][mt][r] = p; rs += p;
                }
            rs += __shfl_xor(rs, 16, 64);
            rs += __shfl_xor(rs, 32, 64);
            lrun[nt] = lrun[nt]*alph[nt] + rs;
            mrun[nt] = mnew;
        }

#pragma unroll
        for (int nt = 0; nt < 2; ++nt) {
            f16* prow = Pt + (wave*32 + 16*nt + ln)*PT_STR + 4*qd;
#pragma unroll
            for (int mt = 0; mt < 4; ++mt)
#pragma unroll
                for (int p2 = 0; p2 < 2; ++p2) {
                    f16x2 pp = { (f16)st[nt][mt][2*p2], (f16)st[nt][mt][2*p2+1] };
                    *(f16x2*)(prow + 16*mt + 2*p2) = pp;
                }
        }

#pragma unroll
        for (int nt = 0; nt < 2; ++nt)
#pragma unroll
            for (int dmt = 0; dmt < 8; ++dmt)
#pragma unroll
                for (int r = 0; r < 4; ++r) o[nt][dmt][r] *= alph[nt];

#pragma unroll
        for (int kc2 = 0; kc2 < 2; ++kc2) {
            f16x8 pf[2];
#pragma unroll
            for (int nt = 0; nt < 2; ++nt) {
                const f16* pr = Pt + (wave*32 + 16*nt + ln)*PT_STR + kc2*32 + 8*qd;
                f16x4 b0 = *(const f16x4*)(pr);
                f16x4 b1 = *(const f16x4*)(pr + 4);
                pf[nt] = __builtin_shufflevector(b0, b1, 0,1,2,3,4,5,6,7);
            }
#pragma unroll
            for (int dmt = 0; dmt < 8; ++dmt) {
                const f16* vr = Vt + (16*dmt + ln)*VT_STR + kc2*32 + 8*qd;
                f16x4 a0 = *(const f16x4*)(vr);
                f16x4 a1 = *(const f16x4*)(vr + 4);
                f16x8 vf = __builtin_shufflevector(a0, a1, 0,1,2,3,4,5,6,7);
#pragma unroll
                for (int nt = 0; nt < 2; ++nt)
                    o[nt][dmt] = __builtin_amdgcn_mfma_f32_16x16x32_f16(vf, pf[nt], o[nt][dmt], 0,0,0);
            }
        }
        __syncthreads();
    }

#pragma unroll
    for (int nt = 0; nt < 2; ++nt) {
        float inv = 1.0f / lrun[nt];
        int qtok = qbase + 16*nt + ln;
        float* orow = og + (size_t)(bb*LL + qtok)*4096 + lhi*DD + 4*qd;
#pragma unroll
        for (int dmt = 0; dmt < 8; ++dmt) {
            float4 x = { o[nt][dmt][0]*inv, o[nt][dmt][1]*inv,
                         o[nt][dmt][2]*inv, o[nt][dmt][3]*inv };
            *(float4*)(orow + 16*dmt) = x;
        }
    }
}

extern "C" void kernel_launch(void* const* d_in, const int* in_sizes, int n_in,
                              void* d_out, int out_size, void* d_ws, size_t ws_size,
                              hipStream_t stream) {
    (void)in_sizes; (void)n_in; (void)out_size;
    const float* q = (const float*)d_in[0];
    const float* k = (const float*)d_in[1];
    const float* v = (const float*)d_in[2];
    float* o = (float*)d_out;
    if (d_ws != nullptr && ws_size >= (size_t)WS_BYTES) {
        hipLaunchKernelGGL(prepack, dim3(8, 64, 2), dim3(256), 0, stream,
                           k, v, (f16*)d_ws);
        hipLaunchKernelGGL(fa_fwd, dim3(1024), dim3(256), 0, stream,
                           q, (const f16*)d_ws, o);
    } else {
        hipLaunchKernelGGL(fa_fwd_fb, dim3(LQ/BM, 64), dim3(256), 0, stream,
                           q, k, v, o);
    }
}

// Round 6
// 202.406 us; speedup vs baseline: 1.3747x; 1.3747x over previous
//
#include <hip/hip_runtime.h>

typedef _Float16 f16;
typedef f16 f16x2 __attribute__((ext_vector_type(2)));
typedef f16 f16x4 __attribute__((ext_vector_type(4)));
typedef f16 f16x8 __attribute__((ext_vector_type(8)));
typedef float f32x4 __attribute__((ext_vector_type(4)));

#define NB   2
#define LL   2048
#define LQ   2048         // q tokens per scrambled batch
#define LKV  512          // unique kv tokens per scrambled batch
#define DD   128
#define BM   128          // q tokens per block (4 waves x 32)
#define BN   64           // kv tokens per iteration
#define NKT  (LKV/BN)     // 8
// fallback-kernel params (first verified kernel)
#define KS_STR 132
#define VT_STR 68
#define PT_STR 68

// workspace layout (halves): K16[g 64][kt 8][chunk 1024][8] then V16t[g 64][kt 8][chunk 1024][8]
#define G_STRIDE 65536ull          // halves per g per tensor
#define WS_BYTES (2ull*64ull*G_STRIDE*2ull)   // 16,777,216 B

// LDS bank swizzle: s(r) = (r&3) | ((r&8)>>1). XOR-involution on the low 3 bits
// of the chunk index. Gives 8 distinct swizzle values over every 16-lane read
// group for BOTH access patterns used below (K rows R: swz3(R)=ln&7;
// V rows R=16dmt+ln: swz3(R)=(ln&3)|((ln&8)>>1), 8 values x 2 lanes).
__device__ inline int swz3(int r) { return (r & 3) | ((r & 8) >> 1); }

#define GLOAD16(gsrc, ldst) \
    __builtin_amdgcn_global_load_lds((const __attribute__((address_space(1))) void*)(gsrc), \
                                     (__attribute__((address_space(3))) void*)(ldst), 16, 0, 0)

// ---------------------------------------------------------------------------
// Pre-pass: K -> f16 (swz3-swizzled chunk order), V -> f16 transposed (swz3).
// Stored chunk c of row r holds logical chunk c ^ swz3(r); a LINEAR
// global_load_lds fill then yields an LDS image read conflict-free at
// byte = r*rowbytes + ((c ^ swz3(r))*16).
// K tile: rows r=kv (64), 16 chunks of 8 halves (d).
// V tile: rows r=d (128), 8 chunks of 8 halves (kv) -- transposed via LDS.
// ---------------------------------------------------------------------------
__global__ __launch_bounds__(256)
void prepack(const float* __restrict__ kg, const float* __restrict__ vg,
             f16* __restrict__ ws)
{
    __shared__ float vtile[64*132];            // f32 staging for V transpose
    const int tid = threadIdx.x;
    const int kt  = blockIdx.x;                // 0..7
    const int g   = blockIdx.y;                // 0..63  (slice offset = g*65536 floats)

    if (blockIdx.z == 0) {
        const float* kb = kg + (size_t)g*65536 + (size_t)kt*8192;  // [64][128] tile
        f16* kout = ws + (size_t)g*G_STRIDE + (size_t)kt*8192;
#pragma unroll
        for (int i = 0; i < 4; ++i) {
            int q = i*256 + tid;               // output chunk index 0..1023
            int r = q >> 4, c = q & 15;
            const float* src = kb + r*128 + ((c ^ swz3(r))*8);
            float4 a = *(const float4*)src;
            float4 b = *(const float4*)(src + 4);
            f16x8 h = { (f16)a.x,(f16)a.y,(f16)a.z,(f16)a.w,
                        (f16)b.x,(f16)b.y,(f16)b.z,(f16)b.w };
            *(f16x8*)(kout + (size_t)q*8) = h;
        }
    } else {
        const float* vb = vg + (size_t)g*65536 + (size_t)kt*8192;  // [64 kv][128 d]
        f16* vout = ws + 64ull*G_STRIDE + (size_t)g*G_STRIDE + (size_t)kt*8192;
#pragma unroll
        for (int i = 0; i < 8; ++i) {
            int f = tid + i*256;
            int row = f >> 5, c4 = f & 31;
            float4 x = *(const float4*)(vb + (size_t)f*4);
            *(float4*)(vtile + row*132 + c4*4) = x;
        }
        __syncthreads();
#pragma unroll
        for (int i = 0; i < 4; ++i) {
            int q = i*256 + tid;               // 0..1023
            int r = q >> 3, c = q & 7;         // r = d row (0..127), c = stored kv chunk
            int kv0 = (c ^ swz3(r))*8;
            f16x8 h;
#pragma unroll
            for (int j = 0; j < 8; ++j) h[j] = (f16)vtile[(kv0+j)*132 + r];
            *(f16x8*)(vout + (size_t)q*8) = h;
        }
    }
}

// ---------------------------------------------------------------------------
// Main flash-attention kernel (R2-verified skeleton + in-lane P handoff).
// kv-row permutation for the QK^T A-operand:
//   A-row m of tile mt  <->  kv = 32*(mt>>1) + 8*(m>>2) + 4*(mt&1) + (m&3)
// so the S^T C/D output (lane qd, tile mt, elem r) holds
//   kv = 32*(mt>>1) + 8*qd + 4*(mt&1) + r
// which is EXACTLY the PV B-operand slot j = 4*(mt&1)+r of chunk kc2 = mt>>1:
//   pf[j] = st[2*kc2 + (j>>2)][j&3]   -- in-lane, zero LDS, zero shuffles.
// Softmax is permutation-invariant. Pt is deleted; LDS = Ks+Vt = 32 KiB.
// Schedule (verified in R2): sync A after QK^T (V(t) landed, Ks free) ->
// issue K(t+1); sync B after PV (K(t+1) landed, Vt free) -> issue V(t+1).
// ---------------------------------------------------------------------------
__global__ __launch_bounds__(256, 3)
void fa_fwd(const float* __restrict__ qg, const f16* __restrict__ ws,
            float* __restrict__ og)
{
    __shared__ __align__(16) f16 Ks[BN*DD];       // [64][128] swizzled, 16384 B
    __shared__ __align__(16) f16 Vt[DD*BN];       // [128][64] swizzled, 16384 B

    const int tid  = threadIdx.x;
    const int wave = tid >> 6;
    const int lane = tid & 63;
    const int ln   = lane & 15;
    const int qd   = lane >> 4;

    // XCD-aware decode: all 16 q-blocks of a batch g share an XCD (bid%8 fixed).
    const int bid = blockIdx.x;                 // 0..1023
    const int qt  = (bid >> 3) & 15;
    const int g   = ((bid & 7) << 3) | (bid >> 7);
    const int bb  = g >> 5;
    const int lhi = g & 31;

    const float* qmat = qg + (size_t)(bb*LL + 64*lhi)*4096;  // [2048][128] f32
    const f16*   kw   = ws + (size_t)g*G_STRIDE;
    const f16*   vw   = ws + (64ull + (size_t)g)*G_STRIDE;

    const int qbase = qt*BM + wave*32;

    auto issueK = [&](int kt) {
#pragma unroll
        for (int i = 0; i < 4; ++i)
            GLOAD16(kw + (size_t)kt*8192 + (size_t)(i*256 + tid)*8,
                    Ks + (i*256 + wave*64)*8);
    };
    auto issueV = [&](int kt) {
#pragma unroll
        for (int i = 0; i < 4; ++i)
            GLOAD16(vw + (size_t)kt*8192 + (size_t)(i*256 + tid)*8,
                    Vt + (i*256 + wave*64)*8);
    };

    issueK(0);
    issueV(0);

    // Q fragments: B-operand of S^T=K*Q^T. frag(nt,kc) slot j = Q''[qbase+16nt+ln][32kc+8qd+j]
    f16x8 qf[2][4];
#pragma unroll
    for (int nt = 0; nt < 2; ++nt) {
        const float* qrow = qmat + (size_t)(qbase + 16*nt + ln)*DD;
#pragma unroll
        for (int kc = 0; kc < 4; ++kc) {
            const float4* qp = (const float4*)(qrow + kc*32 + 8*qd);
            float4 f0 = qp[0], f1 = qp[1];
            f16x8 t = { (f16)f0.x,(f16)f0.y,(f16)f0.z,(f16)f0.w,
                        (f16)f1.x,(f16)f1.y,(f16)f1.z,(f16)f1.w };
            qf[nt][kc] = t;
        }
    }

    f32x4 o[2][8];   // o[nt][dmt][r] = O^T[16*dmt+4*qd+r][q(nt)]
#pragma unroll
    for (int nt = 0; nt < 2; ++nt)
#pragma unroll
        for (int dmt = 0; dmt < 8; ++dmt)
#pragma unroll
            for (int r = 0; r < 4; ++r) o[nt][dmt][r] = 0.0f;

    float mrun[2] = {-1e30f, -1e30f}, lrun[2] = {0.0f, 0.0f};
    const float SC2 = 0.08837890625f * 1.44269504088896340f;  // fp16-rounded scale * log2(e)

    __syncthreads();    // drains vmcnt(0): K(0), V(0) landed

#pragma unroll 1
    for (int t = 0; t < NKT; ++t) {
        // ---- S^T = K*Q^T with permuted A-rows (see header) ----
        f32x4 st[2][4];
#pragma unroll
        for (int nt = 0; nt < 2; ++nt)
#pragma unroll
            for (int mt = 0; mt < 4; ++mt)
#pragma unroll
                for (int r = 0; r < 4; ++r) st[nt][mt][r] = 0.0f;
        __builtin_amdgcn_s_setprio(1);
#pragma unroll
        for (int mt = 0; mt < 4; ++mt) {
            const int R = 32*(mt >> 1) + 8*(ln >> 2) + 4*(mt & 1) + (ln & 3);
#pragma unroll
            for (int kc = 0; kc < 4; ++kc) {
                f16x8 af = *(const f16x8*)(Ks + R*DD + (((kc*4 + qd) ^ swz3(R))*8));
#pragma unroll
                for (int nt = 0; nt < 2; ++nt)
                    st[nt][mt] = __builtin_amdgcn_mfma_f32_16x16x32_f16(af, qf[nt][kc], st[nt][mt], 0,0,0);
            }
        }
        __builtin_amdgcn_s_setprio(0);

        // ---- online softmax (registers only; permutation-invariant) ----
        float alph[2];
#pragma unroll
        for (int nt = 0; nt < 2; ++nt) {
            float mx = -1e30f;
#pragma unroll
            for (int mt = 0; mt < 4; ++mt)
#pragma unroll
                for (int r = 0; r < 4; ++r) {
                    float v = st[nt][mt][r]*SC2; st[nt][mt][r] = v; mx = fmaxf(mx, v);
                }
            mx = fmaxf(mx, __shfl_xor(mx, 16, 64));
            mx = fmaxf(mx, __shfl_xor(mx, 32, 64));
            float mnew = fmaxf(mrun[nt], mx);
            alph[nt] = exp2f(mrun[nt] - mnew);
            float rs = 0.0f;
#pragma unroll
            for (int mt = 0; mt < 4; ++mt)
#pragma unroll
                for (int r = 0; r < 4; ++r) {
                    float p = exp2f(st[nt][mt][r] - mnew);
                    st[nt][mt][r] = p; rs += p;
                }
            rs += __shfl_xor(rs, 16, 64);
            rs += __shfl_xor(rs, 32, 64);
            lrun[nt] = lrun[nt]*alph[nt] + rs;
            mrun[nt] = mnew;
        }

        // ---- sync A: everyone's Ks reads retired; V(t) landed (vm drained) ----
        __syncthreads();
        if (t+1 < NKT) issueK(t+1);   // lands under PV, checked at sync B

        // ---- rescale O^T ----
#pragma unroll
        for (int nt = 0; nt < 2; ++nt)
#pragma unroll
            for (int dmt = 0; dmt < 8; ++dmt)
#pragma unroll
                for (int r = 0; r < 4; ++r) o[nt][dmt][r] *= alph[nt];

        // ---- O^T += V^T * P^T : A = swizzled Vt rows, B = in-lane pf ----
#pragma unroll
        for (int kc2 = 0; kc2 < 2; ++kc2) {
            f16x8 pf[2];
#pragma unroll
            for (int nt = 0; nt < 2; ++nt) {
                f16x8 pp = { (f16)st[nt][2*kc2+0][0], (f16)st[nt][2*kc2+0][1],
                             (f16)st[nt][2*kc2+0][2], (f16)st[nt][2*kc2+0][3],
                             (f16)st[nt][2*kc2+1][0], (f16)st[nt][2*kc2+1][1],
                             (f16)st[nt][2*kc2+1][2], (f16)st[nt][2*kc2+1][3] };
                pf[nt] = pp;
            }
            __builtin_amdgcn_s_setprio(1);
#pragma unroll
            for (int dmt = 0; dmt < 8; ++dmt) {
                const int R = 16*dmt + ln;
                f16x8 vf = *(const f16x8*)(Vt + R*BN + (((kc2*4 + qd) ^ swz3(R))*8));
#pragma unroll
                for (int nt = 0; nt < 2; ++nt)
                    o[nt][dmt] = __builtin_amdgcn_mfma_f32_16x16x32_f16(vf, pf[nt], o[nt][dmt], 0,0,0);
            }
            __builtin_amdgcn_s_setprio(0);
        }

        // ---- sync B: everyone's Vt reads retired; K(t+1) landed (vm drained) ----
        __syncthreads();
        if (t+1 < NKT) issueV(t+1);   // lands under next QK^T + softmax
    }

    // ---- epilogue: O^T/l -> og[(bb*2048+t)*4096 + lhi*128 + d] ----
#pragma unroll
    for (int nt = 0; nt < 2; ++nt) {
        float inv = 1.0f / lrun[nt];
        int qtok = qbase + 16*nt + ln;
        float* orow = og + (size_t)(bb*LL + qtok)*4096 + lhi*DD + 4*qd;
#pragma unroll
        for (int dmt = 0; dmt < 8; ++dmt) {
            float4 x = { o[nt][dmt][0]*inv, o[nt][dmt][1]*inv,
                         o[nt][dmt][2]*inv, o[nt][dmt][3]*inv };
            *(float4*)(orow + 16*dmt) = x;
        }
    }
}

// ---------------------------------------------------------------------------
// Fallback (first verified kernel) for the case ws_size < WS_BYTES.
// ---------------------------------------------------------------------------
__global__ __launch_bounds__(256, 2)
void fa_fwd_fb(const float* __restrict__ qg,
               const float* __restrict__ kg,
               const float* __restrict__ vg,
               float* __restrict__ og)
{
    __shared__ __align__(16) f16 smem[BN*KS_STR + DD*VT_STR + BM*PT_STR];
    f16* Ks = smem;
    f16* Vt = smem + BN*KS_STR;
    f16* Pt = smem + BN*KS_STR + DD*VT_STR;

    const int tid  = threadIdx.x;
    const int wave = tid >> 6;
    const int lane = tid & 63;
    const int ln   = lane & 15;
    const int qd   = lane >> 4;

    const int qt   = blockIdx.x;
    const int g    = blockIdx.y;
    const int bb   = g >> 5;
    const int lhi  = g & 31;

    const float* qmat = qg + (size_t)(bb*LL + 64*lhi)*4096;
    const float* kmat = kg + (size_t)(bb*LL + 64*lhi)*1024;
    const float* vmat = vg + (size_t)(bb*LL + 64*lhi)*1024;

    const int qbase = qt*BM + wave*32;

    f16x8 qf[2][4];
#pragma unroll
    for (int nt = 0; nt < 2; ++nt) {
        const float* qrow = qmat + (size_t)(qbase + 16*nt + ln)*DD;
#pragma unroll
        for (int kc = 0; kc < 4; ++kc) {
            const float4* qp = (const float4*)(qrow + kc*32 + 8*qd);
            float4 f0 = qp[0], f1 = qp[1];
            f16x8 t = { (f16)f0.x,(f16)f0.y,(f16)f0.z,(f16)f0.w,
                        (f16)f1.x,(f16)f1.y,(f16)f1.z,(f16)f1.w };
            qf[nt][kc] = t;
        }
    }

    f32x4 o[2][8];
#pragma unroll
    for (int nt = 0; nt < 2; ++nt)
#pragma unroll
        for (int dmt = 0; dmt < 8; ++dmt)
#pragma unroll
            for (int r = 0; r < 4; ++r) o[nt][dmt][r] = 0.0f;

    float mrun[2] = {-1e30f, -1e30f}, lrun[2] = {0.0f, 0.0f};
    const float SC2 = 0.08837890625f * 1.44269504088896340f;

    for (int kt = 0; kt < LKV/BN; ++kt) {
        const float* kb = kmat + kt*BN*DD;
        const float* vb = vmat + kt*BN*DD;

#pragma unroll
        for (int i = 0; i < 8; ++i) {
            int f = tid + i*256;
            int row = f >> 5, c4 = f & 31;
            float4 x = *(const float4*)(kb + f*4);
            f16x4 h4 = { (f16)x.x,(f16)x.y,(f16)x.z,(f16)x.w };
            *(f16x4*)(Ks + row*KS_STR + c4*4) = h4;
        }
#pragma unroll
        for (int i = 0; i < 8; ++i) {
            int f = tid + i*256;
            int kvr = f & 63, c4 = f >> 6;
            float4 x = *(const float4*)(vb + (size_t)kvr*DD + c4*4);
            Vt[(c4*4+0)*VT_STR + kvr] = (f16)x.x;
            Vt[(c4*4+1)*VT_STR + kvr] = (f16)x.y;
            Vt[(c4*4+2)*VT_STR + kvr] = (f16)x.z;
            Vt[(c4*4+3)*VT_STR + kvr] = (f16)x.w;
        }
        __syncthreads();

        f32x4 st[2][4];
#pragma unroll
        for (int nt = 0; nt < 2; ++nt)
#pragma unroll
            for (int mt = 0; mt < 4; ++mt)
#pragma unroll
                for (int r = 0; r < 4; ++r) st[nt][mt][r] = 0.0f;
#pragma unroll
        for (int mt = 0; mt < 4; ++mt) {
            const f16* kr = Ks + (16*mt + ln)*KS_STR + 8*qd;
#pragma unroll
            for (int kc = 0; kc < 4; ++kc) {
                f16x4 a0 = *(const f16x4*)(kr + kc*32);
                f16x4 a1 = *(const f16x4*)(kr + kc*32 + 4);
                f16x8 af = __builtin_shufflevector(a0, a1, 0,1,2,3,4,5,6,7);
#pragma unroll
                for (int nt = 0; nt < 2; ++nt)
                    st[nt][mt] = __builtin_amdgcn_mfma_f32_16x16x32_f16(af, qf[nt][kc], st[nt][mt], 0,0,0);
            }
        }

        float alph[2];
#pragma unroll
        for (int nt = 0; nt < 2; ++nt) {
            float mx = -1e30f;
#pragma unroll
            for (int mt = 0; mt < 4; ++mt)
#pragma unroll
                for (int r = 0; r < 4; ++r) {
                    float v = st[nt][mt][r]*SC2; st[nt][mt][r] = v; mx = fmaxf(mx, v);
                }
            mx = fmaxf(mx, __shfl_xor(mx, 16, 64));
            mx = fmaxf(mx, __shfl_xor(mx, 32, 64));
            float mnew = fmaxf(mrun[nt], mx);
            alph[nt] = exp2f(mrun[nt] - mnew);
            float rs = 0.0f;
#pragma unroll
            for (int mt = 0; mt < 4; ++mt)
#pragma unroll
                for (int r = 0; r < 4; ++r) {
                    float p = exp2f(st[nt][mt][r] - mnew);
                    st[nt][mt][r] = p; rs += p;
                }
            rs += __shfl_xor(rs, 16, 64);
            rs += __shfl_xor(rs, 32, 64);
            lrun[nt] = lrun[nt]*alph[nt] + rs;
            mrun[nt] = mnew;
        }

#pragma unroll
        for (int nt = 0; nt < 2; ++nt) {
            f16* prow = Pt + (wave*32 + 16*nt + ln)*PT_STR + 4*qd;
#pragma unroll
            for (int mt = 0; mt < 4; ++mt)
#pragma unroll
                for (int p2 = 0; p2 < 2; ++p2) {
                    f16x2 pp = { (f16)st[nt][mt][2*p2], (f16)st[nt][mt][2*p2+1] };
                    *(f16x2*)(prow + 16*mt + 2*p2) = pp;
                }
        }

#pragma unroll
        for (int nt = 0; nt < 2; ++nt)
#pragma unroll
            for (int dmt = 0; dmt < 8; ++dmt)
#pragma unroll
                for (int r = 0; r < 4; ++r) o[nt][dmt][r] *= alph[nt];

#pragma unroll
        for (int kc2 = 0; kc2 < 2; ++kc2) {
            f16x8 pf[2];
#pragma unroll
            for (int nt = 0; nt < 2; ++nt) {
                const f16* pr = Pt + (wave*32 + 16*nt + ln)*PT_STR + kc2*32 + 8*qd;
                f16x4 b0 = *(const f16x4*)(pr);
                f16x4 b1 = *(const f16x4*)(pr + 4);
                pf[nt] = __builtin_shufflevector(b0, b1, 0,1,2,3,4,5,6,7);
            }
#pragma unroll
            for (int dmt = 0; dmt < 8; ++dmt) {
                const f16* vr = Vt + (16*dmt + ln)*VT_STR + kc2*32 + 8*qd;
                f16x4 a0 = *(const f16x4*)(vr);
                f16x4 a1 = *(const f16x4*)(vr + 4);
                f16x8 vf = __builtin_shufflevector(a0, a1, 0,1,2,3,4,5,6,7);
#pragma unroll
                for (int nt = 0; nt < 2; ++nt)
                    o[nt][dmt] = __builtin_amdgcn_mfma_f32_16x16x32_f16(vf, pf[nt], o[nt][dmt], 0,0,0);
            }
        }
        __syncthreads();
    }

#pragma unroll
    for (int nt = 0; nt < 2; ++nt) {
        float inv = 1.0f / lrun[nt];
        int qtok = qbase + 16*nt + ln;
        float* orow = og + (size_t)(bb*LL + qtok)*4096 + lhi*DD + 4*qd;
#pragma unroll
        for (int dmt = 0; dmt < 8; ++dmt) {
            float4 x = { o[nt][dmt][0]*inv, o[nt][dmt][1]*inv,
                         o[nt][dmt][2]*inv, o[nt][dmt][3]*inv };
            *(float4*)(orow + 16*dmt) = x;
        }
    }
}

extern "C" void kernel_launch(void* const* d_in, const int* in_sizes, int n_in,
                              void* d_out, int out_size, void* d_ws, size_t ws_size,
                              hipStream_t stream) {
    (void)in_sizes; (void)n_in; (void)out_size;
    const float* q = (const float*)d_in[0];
    const float* k = (const float*)d_in[1];
    const float* v = (const float*)d_in[2];
    float* o = (float*)d_out;
    if (d_ws != nullptr && ws_size >= (size_t)WS_BYTES) {
        hipLaunchKernelGGL(prepack, dim3(8, 64, 2), dim3(256), 0, stream,
                           k, v, (f16*)d_ws);
        hipLaunchKernelGGL(fa_fwd, dim3(1024), dim3(256), 0, stream,
                           q, (const f16*)d_ws, o);
    } else {
        hipLaunchKernelGGL(fa_fwd_fb, dim3(LQ/BM, 64), dim3(256), 0, stream,
                           q, k, v, o);
    }
}